// Round 1
// baseline (925.770 us; speedup 1.0000x reference)
//
#include <hip/hip_runtime.h>
#include <hip/hip_bf16.h>

#define NNODES 500000
#define KDIM 100
#define KP1 128
#define HDIM 256
#define MBLK 64
#define THREADS 256

typedef __attribute__((ext_vector_type(8))) short bf16x8;
typedef __attribute__((ext_vector_type(4))) float f32x4;

__device__ __forceinline__ unsigned short f2bf(float f) {
    union { float f; unsigned u; } v; v.f = f;
    unsigned r = v.u + 0x7fffu + ((v.u >> 16) & 1u);   // round-to-nearest-even
    return (unsigned short)(r >> 16);
}
__device__ __forceinline__ float bf2f(unsigned short h) {
    union { unsigned u; float f; } v; v.u = ((unsigned)h) << 16; return v.f;
}
__device__ __forceinline__ float fast_tanh(float x) {
    float e = __expf(2.0f * x);          // x->+inf: e=inf -> 1; x->-inf: e=0 -> -1
    return 1.0f - 2.0f / (e + 1.0f);
}

// Pack W (ksrc x 256, f32 row-major) into bf16 B-fragment tiles for
// mfma_f32_16x16x32_bf16. Tile (kt,nt) = 512 bf16 at (kt*16+nt)*512;
// element lane*8+j = W[kt*32 + (lane>>4)*8 + j][nt*16 + (lane&15)], zero-pad k>=ksrc.
__global__ void pack_w(const float* __restrict__ src, unsigned short* __restrict__ dst,
                       int ksrc, int kpad) {
    int t = blockIdx.x * blockDim.x + threadIdx.x;
    if (t >= kpad * HDIM) return;
    int tile = t >> 9;
    int r = t & 511;
    int lane = r >> 3, j = r & 7;
    int kt = tile >> 4;
    int nt = tile & 15;
    int k = kt * 32 + ((lane >> 4) << 3) + j;
    int n = nt * 16 + (lane & 15);
    float v = (k < ksrc) ? src[k * HDIM + n] : 0.0f;
    dst[t] = f2bf(v);
}

// LDS layout: two regions; element (row,col) at row*STRIDE + ((col>>3)^(row&7))*8 + (col&7)
// (XOR swizzle on 8-element granules -> 2-way max bank aliasing on ds_read_b128).

template<int KSTEPS, int IN_STRIDE>
__device__ __forceinline__ void layer(const unsigned short* __restrict__ inbuf,
                                      unsigned short* __restrict__ outbuf,
                                      const unsigned short* __restrict__ wp,
                                      const float* __restrict__ bias, int tid) {
    const int lane = tid & 63;
    const int w = tid >> 6;           // wave id 0..3, owns cols [w*64, w*64+64)
    const int lrow = lane & 15;
    const int quad = lane >> 4;

    f32x4 acc[4][4];
#pragma unroll
    for (int mt = 0; mt < 4; mt++)
#pragma unroll
        for (int nt = 0; nt < 4; nt++) acc[mt][nt] = (f32x4){0.f, 0.f, 0.f, 0.f};

#pragma unroll 2
    for (int ks = 0; ks < KSTEPS; ks++) {
        bf16x8 a[4], b[4];
        const int gk = ks * 4 + quad;               // k-granule index
#pragma unroll
        for (int mt = 0; mt < 4; mt++) {
            const int row = mt * 16 + lrow;
            a[mt] = *(const bf16x8*)(inbuf + row * IN_STRIDE + ((gk ^ (row & 7)) << 3));
        }
#pragma unroll
        for (int nt = 0; nt < 4; nt++) {
            const int tile = ks * 16 + (w * 4 + nt);
            b[nt] = *(const bf16x8*)(wp + tile * 512 + lane * 8);
        }
#pragma unroll
        for (int mt = 0; mt < 4; mt++)
#pragma unroll
            for (int nt = 0; nt < 4; nt++)
                acc[mt][nt] = __builtin_amdgcn_mfma_f32_16x16x32_bf16(a[mt], b[nt], acc[mt][nt], 0, 0, 0);
    }

    // epilogue: bias + tanh -> bf16 into outbuf (C/D map: col=lane&15, row=quad*4+reg)
    float bcol[4];
#pragma unroll
    for (int nt = 0; nt < 4; nt++) bcol[nt] = bias[(w * 4 + nt) * 16 + lrow];
#pragma unroll
    for (int mt = 0; mt < 4; mt++)
#pragma unroll
        for (int nt = 0; nt < 4; nt++) {
            const int col = (w * 4 + nt) * 16 + lrow;
            const int cg = col >> 3, cr = col & 7;
#pragma unroll
            for (int reg = 0; reg < 4; reg++) {
                const int row = mt * 16 + quad * 4 + reg;
                float v = fast_tanh(acc[mt][nt][reg] + bcol[nt]);
                outbuf[row * HDIM + ((cg ^ (row & 7)) << 3) + cr] = f2bf(v);
            }
        }
    __syncthreads();
}

__launch_bounds__(THREADS, 2)
__global__ void mlp_kernel(const float* __restrict__ ea,
                           const unsigned short* __restrict__ w1p,
                           const unsigned short* __restrict__ w2p,
                           const unsigned short* __restrict__ w3p,
                           const float* __restrict__ b1,
                           const float* __restrict__ b2,
                           const float* __restrict__ b3,
                           const float* __restrict__ w4,
                           const float* __restrict__ b4,
                           float* __restrict__ out) {
    __shared__ char smem[65536];
    unsigned short* r0 = (unsigned short*)smem;                 // 64 x 128 (e) then h2
    unsigned short* r1 = (unsigned short*)(smem + 32768);       // h1 then h3

    const int tid = threadIdx.x;
    const long rowbase = (long)blockIdx.x * MBLK;

    // stage e (64 rows x 100 f32 -> bf16, pad to 128) into r0, stride 128, swizzled
    for (int i = tid; i < MBLK * 25; i += THREADS) {
        int row = i / 25, q = i - row * 25;          // q-th float4 of the row
        long grow = rowbase + row; if (grow >= NNODES) grow = NNODES - 1;
        float4 v = ((const float4*)ea)[grow * 25 + q];
        unsigned short* p = r0 + row * KP1 + ((((q >> 1)) ^ (row & 7)) << 3) + ((q & 1) << 2);
        p[0] = f2bf(v.x); p[1] = f2bf(v.y); p[2] = f2bf(v.z); p[3] = f2bf(v.w);
    }
    for (int i = tid; i < MBLK * 28; i += THREADS) { // zero-pad k=100..127
        int row = i / 28; int col = 100 + (i - row * 28);
        r0[row * KP1 + (((col >> 3) ^ (row & 7)) << 3) + (col & 7)] = 0;
    }
    __syncthreads();

    layer<4, KP1>(r0, r1, w1p, b1, tid);    // L1: (64x128)@(128x256) tanh
    layer<8, HDIM>(r1, r0, w2p, b2, tid);   // L2
    layer<8, HDIM>(r0, r1, w3p, b3, tid);   // L3

    // head: out = sigmoid(h3 . W4 + b4); 4 lanes per row, 64 elems each
    {
        const int row = tid >> 2;
        const int part = tid & 3;
        float s = 0.f;
        const int gbase = part * 8;
#pragma unroll
        for (int g = 0; g < 8; g++) {
            const unsigned short* hp = r1 + row * HDIM + (((gbase + g) ^ (row & 7)) << 3);
            const float* wp = w4 + (gbase + g) * 8;
#pragma unroll
            for (int j = 0; j < 8; j++) s += bf2f(hp[j]) * wp[j];
        }
        s += __shfl_xor(s, 1);
        s += __shfl_xor(s, 2);
        if (part == 0) {
            long grow = rowbase + row;
            if (grow < NNODES) out[grow] = 1.0f / (1.0f + __expf(-(s + b4[0])));
        }
    }
}

extern "C" void kernel_launch(void* const* d_in, const int* in_sizes, int n_in,
                              void* d_out, int out_size, void* d_ws, size_t ws_size,
                              hipStream_t stream) {
    // inputs: 0:x 1:edge_index 2:edge_attr 3:W1 4:b1 5:W2 6:b2 7:W3 8:b3 9:W4 10:b4
    const float* ea = (const float*)d_in[2];
    const float* W1 = (const float*)d_in[3];
    const float* b1 = (const float*)d_in[4];
    const float* W2 = (const float*)d_in[5];
    const float* b2 = (const float*)d_in[6];
    const float* W3 = (const float*)d_in[7];
    const float* b3 = (const float*)d_in[8];
    const float* W4 = (const float*)d_in[9];
    const float* b4 = (const float*)d_in[10];
    float* out = (float*)d_out;

    unsigned short* w1p = (unsigned short*)d_ws;       // 128*256 bf16
    unsigned short* w2p = w1p + KP1 * HDIM;            // 256*256
    unsigned short* w3p = w2p + HDIM * HDIM;           // 256*256

    pack_w<<<(KP1 * HDIM + 255) / 256, 256, 0, stream>>>(W1, w1p, KDIM, KP1);
    pack_w<<<(HDIM * HDIM + 255) / 256, 256, 0, stream>>>(W2, w2p, HDIM, HDIM);
    pack_w<<<(HDIM * HDIM + 255) / 256, 256, 0, stream>>>(W3, w3p, HDIM, HDIM);

    const int grid = (NNODES + MBLK - 1) / MBLK;       // 7813
    mlp_kernel<<<grid, THREADS, 0, stream>>>(ea, w1p, w2p, w3p, b1, b2, b3, W4, b4, out);
}

// Round 2
// 869.473 us; speedup vs baseline: 1.0647x; 1.0647x over previous
//
#include <hip/hip_runtime.h>

#define NNODES 500000
#define KDIM 100
#define KP1 128
#define HDIM 256
#define MBLK 32
#define THREADS 256

typedef __attribute__((ext_vector_type(8))) short bf16x8;
typedef __attribute__((ext_vector_type(4))) float f32x4;

__device__ __forceinline__ unsigned rnd_bf(float f) {
    union { float f; unsigned u; } v; v.f = f;
    return v.u + 0x7fffu + ((v.u >> 16) & 1u);      // rne bias
}
__device__ __forceinline__ unsigned pack2(float lo, float hi) {
    return (rnd_bf(lo) >> 16) | (rnd_bf(hi) & 0xffff0000u);
}
__device__ __forceinline__ float fast_tanh(float x) {
    float e = __expf(2.0f * x);
    return 1.0f - 2.0f / (e + 1.0f);
}
__device__ __forceinline__ float bflo(unsigned u) {
    union { unsigned u; float f; } v; v.u = u << 16; return v.f;
}
__device__ __forceinline__ float bfhi(unsigned u) {
    union { unsigned u; float f; } v; v.u = u & 0xffff0000u; return v.f;
}

// Pack weights into MFMA A-operand tiles (A = W^T): tile (kt, m16) at
// (kt*16+m16)*512; element lane*8+j = W[kt*32 + (lane>>4)*8 + j][m16*16 + (lane&15)].
// (Same layout as the round-1 verified B-pack — B[k][n] of W == A[m][k] of W^T.)
__global__ void pack_all(const float* __restrict__ W1, const float* __restrict__ W2,
                         const float* __restrict__ W3,
                         unsigned short* __restrict__ w1p, unsigned short* __restrict__ w2p,
                         unsigned short* __restrict__ w3p) {
    int t = blockIdx.x * 256 + threadIdx.x;
    const float* src; unsigned short* dst; int ksrc;
    if (t < KP1 * HDIM)                    { src = W1; dst = w1p; ksrc = KDIM; }
    else if (t < KP1 * HDIM + HDIM * HDIM) { t -= KP1 * HDIM; src = W2; dst = w2p; ksrc = HDIM; }
    else                                   { t -= KP1 * HDIM + HDIM * HDIM; src = W3; dst = w3p; ksrc = HDIM; }
    int tile = t >> 9, r = t & 511, lane = r >> 3, j = r & 7;
    int kt = tile >> 4, m16 = tile & 15;
    int k = kt * 32 + ((lane >> 4) << 3) + j;
    int n = m16 * 16 + (lane & 15);
    float v = (k < ksrc) ? src[k * HDIM + n] : 0.0f;
    dst[tile * 512 + r] = (unsigned short)(rnd_bf(v) >> 16);
}

// Activations in LDS: [node][feature], element (n,f) at n*STRIDE + ((f>>3)^(n&7))*8 + (f&7).
// A = weight fragment (global, prepacked), B = activation fragment (LDS b128),
// D: row = feature (quad*4+reg -> consecutive!), col = node -> b64 epilogue stores.
template<int KSTEPS, int IN_STRIDE>
__device__ __forceinline__ void layer(const unsigned short* inbuf,
                                      unsigned short* outbuf,
                                      const unsigned short* __restrict__ wp,
                                      const float* __restrict__ bias, int tid) {
    const int lane = tid & 63;
    const int w = tid >> 6;            // wave owns features [w*64, w*64+64), all 32 nodes
    const int lrow = lane & 15;
    const int quad = lane >> 4;
    const int s = lrow & 7;            // swizzle key: node&7 == lrow&7 for both n-tiles

    f32x4 acc[4][2];
#pragma unroll
    for (int mt = 0; mt < 4; mt++) {
        f32x4 bv = *(const f32x4*)(bias + w * 64 + mt * 16 + quad * 4);
#pragma unroll
        for (int nt = 0; nt < 2; nt++) acc[mt][nt] = bv;
    }

    const unsigned short* wpw = wp + (w * 4) * 512 + lane * 8;

#pragma unroll 2
    for (int ks = 0; ks < KSTEPS; ks++) {
        const int gk = ks * 4 + quad;
        const int off = ((gk ^ s) << 3);
        bf16x8 b[2], a[4];
#pragma unroll
        for (int nt = 0; nt < 2; nt++)
            b[nt] = *(const bf16x8*)(inbuf + (nt * 16 + lrow) * IN_STRIDE + off);
#pragma unroll
        for (int mt = 0; mt < 4; mt++)
            a[mt] = *(const bf16x8*)(wpw + (ks * 16 + mt) * 512);
#pragma unroll
        for (int mt = 0; mt < 4; mt++)
#pragma unroll
            for (int nt = 0; nt < 2; nt++)
                acc[mt][nt] = __builtin_amdgcn_mfma_f32_16x16x32_bf16(a[mt], b[nt], acc[mt][nt], 0, 0, 0);
    }

#pragma unroll
    for (int mt = 0; mt < 4; mt++) {
        const int g = w * 8 + mt * 2 + (quad >> 1);      // feature granule
#pragma unroll
        for (int nt = 0; nt < 2; nt++) {
            const int node = nt * 16 + lrow;
            unsigned short* p = outbuf + node * HDIM + ((g ^ s) << 3) + ((quad & 1) << 2);
            f32x4 v = acc[mt][nt];
            uint2 pk;
            pk.x = pack2(fast_tanh(v[0]), fast_tanh(v[1]));
            pk.y = pack2(fast_tanh(v[2]), fast_tanh(v[3]));
            *(uint2*)p = pk;
        }
    }
    __syncthreads();
}

__launch_bounds__(THREADS, 5)
__global__ void mlp_kernel(const float* __restrict__ ea,
                           const unsigned short* __restrict__ w1p,
                           const unsigned short* __restrict__ w2p,
                           const unsigned short* __restrict__ w3p,
                           const float* __restrict__ b1,
                           const float* __restrict__ b2,
                           const float* __restrict__ b3,
                           const float* __restrict__ w4,
                           const float* __restrict__ b4,
                           float* __restrict__ out) {
    __shared__ unsigned short sm[2][MBLK * HDIM];   // 2 x 16 KiB
    unsigned short* r0 = sm[0];                     // e (stride 128), then h2
    unsigned short* r1 = sm[1];                     // h1, then h3

    const int tid = threadIdx.x;
    const long rowbase = (long)blockIdx.x * MBLK;   // grid divides exactly

    // stage e: 32 rows x 25 float4 -> bf16 (swizzled, stride KP1)
    const float4* eav = (const float4*)(ea + rowbase * KDIM);
    for (int i = tid; i < MBLK * 25; i += THREADS) {
        int row = i / 25;
        int q = i - row * 25;
        float4 v = eav[i];
        unsigned short* p = r0 + row * KP1 + ((((q >> 1)) ^ (row & 7)) << 3) + ((q & 1) << 2);
        *(uint2*)p = make_uint2(pack2(v.x, v.y), pack2(v.z, v.w));
    }
    // zero-pad cols 100..127 (granule 12 upper half + granules 13..15)
    for (int i = tid; i < MBLK * 4; i += THREADS) {
        int row = i >> 2, c = i & 3;
        if (c == 0) {
            unsigned short* p = r0 + row * KP1 + ((12 ^ (row & 7)) << 3) + 4;
            *(uint2*)p = make_uint2(0u, 0u);
        } else {
            unsigned short* p = r0 + row * KP1 + (((12 + c) ^ (row & 7)) << 3);
            *(uint4*)p = make_uint4(0u, 0u, 0u, 0u);
        }
    }
    __syncthreads();

    layer<4, KP1>(r0, r1, w1p, b1, tid);     // L1: (32x128)@(128x256) tanh
    layer<8, HDIM>(r1, r0, w2p, b2, tid);    // L2
    layer<8, HDIM>(r0, r1, w3p, b3, tid);    // L3

    // head: out = sigmoid(h3 . W4 + b4); 8 lanes per node, 32 feats each
    {
        const int node = tid >> 3, part = tid & 7;
        const int s = node & 7;
        float sacc = 0.0f;
#pragma unroll
        for (int gg = 0; gg < 4; gg++) {
            const int g = part * 4 + gg;
            const uint4 hv = *(const uint4*)(r1 + node * HDIM + ((g ^ s) << 3));
            const float4 w0 = *(const float4*)(w4 + g * 8);
            const float4 w1 = *(const float4*)(w4 + g * 8 + 4);
            sacc += bflo(hv.x) * w0.x + bfhi(hv.x) * w0.y;
            sacc += bflo(hv.y) * w0.z + bfhi(hv.y) * w0.w;
            sacc += bflo(hv.z) * w1.x + bfhi(hv.z) * w1.y;
            sacc += bflo(hv.w) * w1.z + bfhi(hv.w) * w1.w;
        }
        sacc += __shfl_xor(sacc, 1);
        sacc += __shfl_xor(sacc, 2);
        sacc += __shfl_xor(sacc, 4);
        if (part == 0) out[rowbase + node] = 1.0f / (1.0f + __expf(-(sacc + b4[0])));
    }
}

extern "C" void kernel_launch(void* const* d_in, const int* in_sizes, int n_in,
                              void* d_out, int out_size, void* d_ws, size_t ws_size,
                              hipStream_t stream) {
    // inputs: 0:x 1:edge_index 2:edge_attr 3:W1 4:b1 5:W2 6:b2 7:W3 8:b3 9:W4 10:b4
    const float* ea = (const float*)d_in[2];
    const float* W1 = (const float*)d_in[3];
    const float* b1 = (const float*)d_in[4];
    const float* W2 = (const float*)d_in[5];
    const float* b2 = (const float*)d_in[6];
    const float* W3 = (const float*)d_in[7];
    const float* b3 = (const float*)d_in[8];
    const float* W4 = (const float*)d_in[9];
    const float* b4 = (const float*)d_in[10];
    float* out = (float*)d_out;

    unsigned short* w1p = (unsigned short*)d_ws;       // 128*256 bf16
    unsigned short* w2p = w1p + KP1 * HDIM;            // 256*256
    unsigned short* w3p = w2p + HDIM * HDIM;           // 256*256

    const int total = KP1 * HDIM + 2 * HDIM * HDIM;    // 163840
    pack_all<<<total / 256, 256, 0, stream>>>(W1, W2, W3, w1p, w2p, w3p);

    mlp_kernel<<<NNODES / MBLK, THREADS, 0, stream>>>(ea, w1p, w2p, w3p,
                                                      b1, b2, b3, W4, b4, out);
}